// Round 4
// baseline (249.829 us; speedup 1.0000x reference)
//
#include <hip/hip_runtime.h>

#define NB 32
#define NP 512
#define NS 1024
#define NH 1024
#define NR 256
#define K3 3072

#define BM 32
#define BKS 128   // K-chunk (of H) per barrier stage -> 512 B contiguous per source row
#define KP2 132   // padded LDS pitch in shorts (264 B; bank stride 66 ≡ 2 mod 32 -> uniform 8/bank)

typedef short short8 __attribute__((ext_vector_type(8)));
typedef __bf16 bf16x8 __attribute__((ext_vector_type(8)));
typedef float f32x4 __attribute__((ext_vector_type(4)));

__device__ __forceinline__ unsigned short f2bf(float f) {
  unsigned u = __builtin_bit_cast(unsigned, f);
  u += 0x7fffu + ((u >> 16) & 1u);   // round-to-nearest-even
  return (unsigned short)(u >> 16);
}

__device__ __forceinline__ f32x4 mfma_bf16(short8 a, short8 b, f32x4 c) {
  return __builtin_amdgcn_mfma_f32_16x16x32_bf16(
      __builtin_bit_cast(bf16x8, a), __builtin_bit_cast(bf16x8, b), c, 0, 0, 0);
}

// W fp32 [256][3072] -> FRAGMENT-MAJOR bf16 in ws:
//   WbF[kc][n16][lane] (short8), kc = k3/32 (96), n16 = n/16 (16), lane = lr + 16*lg.
//   Element: W[n16*16 + lr][kc*32 + lg*8 + e].  A wave's B-fragment load is one
//   contiguous 1 KB burst.
__global__ void wconv_kernel(const float* __restrict__ W,
                             unsigned short* __restrict__ WbF) {
  int i = blockIdx.x * blockDim.x + threadIdx.x;   // short8 id, 98304 total
  int lane = i & 63, n16 = (i >> 6) & 15, kc = i >> 10;
  int lr = lane & 15, lg = lane >> 4;
  const float* src = W + (size_t)(n16 * 16 + lr) * K3 + kc * 32 + lg * 8;
  float4 a = *(const float4*)src;
  float4 b = *(const float4*)(src + 4);
  short8 o;
  o[0] = (short)f2bf(a.x); o[1] = (short)f2bf(a.y);
  o[2] = (short)f2bf(a.z); o[3] = (short)f2bf(a.w);
  o[4] = (short)f2bf(b.x); o[5] = (short)f2bf(b.y);
  o[6] = (short)f2bf(b.z); o[7] = (short)f2bf(b.w);
  *(short8*)(WbF + (size_t)i * 8) = o;
}

// Fused gather + 3-part bf16 MFMA GEMM.
// Grid: 512 blocks (M-tiles of 32 pairs) -> 2 independent blocks/CU (decoupled
// barriers). 256 threads = 4 waves; wave w owns cols [w*64, w*64+64), tile 32x64.
// K-loop: 8 stages of BKS=128 cols of H; each stage gathers 512 B contiguous
// per source row (vs 256 B before) for DRAM-page/burst efficiency, stages
// h/t/prod 32x128 bf16 tiles in double-buffered LDS; W frags stream from L1/L2.
__global__ __launch_bounds__(256, 2) void gemm_kernel(
    const int* __restrict__ pairs, const float* __restrict__ hs,
    const unsigned short* __restrict__ WbF, const float* __restrict__ bias,
    float* __restrict__ out) {
  __shared__ __align__(16) unsigned short sA[2][3][BM][KP2];  // 50688 B

  const int tid   = threadIdx.x;
  const int blk   = blockIdx.x;
  const int batch = blk >> 4;          // 16 M-tiles per batch (512/32)
  const int m0    = blk * BM;          // global pair-row base

  // 8 threads per pair; thread owns cols [q*16, q*16+16) of each stage window
  const int pairi = tid >> 3;
  const int q     = tid & 7;
  int4 pr = ((const int4*)pairs)[m0 + pairi];
  const float* hb  = hs + (size_t)batch * NS * NH;
  const float* pr0 = hb + (size_t)pr.x * NH + q * 16;  // h_start
  const float* pr1 = hb + (size_t)pr.y * NH + q * 16;  // h_end
  const float* pr2 = hb + (size_t)pr.z * NH + q * 16;  // t_start
  const float* pr3 = hb + (size_t)pr.w * NH + q * 16;  // t_end

  // --- MFMA lane mapping ---
  const int lane = tid & 63;
  const int w    = tid >> 6;           // wave 0..3, cols w*64..w*64+64
  const int lr   = lane & 15;
  const int lg   = lane >> 4;

  // frag-major W: short addr = kc*8192 + n16*512 + lane*8; this wave: n16 = w*4 + j
  const unsigned short* wb = WbF + (size_t)(w * 4) * 512 + (size_t)lane * 8;

  f32x4 acc[2][4];
#pragma unroll
  for (int i = 0; i < 2; ++i)
#pragma unroll
    for (int j = 0; j < 4; ++j) acc[i][j] = (f32x4){0.f, 0.f, 0.f, 0.f};

  // raw gather prefetch: 4 rows x 16 cols = 16 float4
  float4 ld[16];

  auto load_stage = [&](int s) {
    const int o = s * BKS;
#pragma unroll
    for (int jj = 0; jj < 4; ++jj) ld[jj]      = *(const float4*)(pr0 + o + 4 * jj);
#pragma unroll
    for (int jj = 0; jj < 4; ++jj) ld[4 + jj]  = *(const float4*)(pr1 + o + 4 * jj);
#pragma unroll
    for (int jj = 0; jj < 4; ++jj) ld[8 + jj]  = *(const float4*)(pr2 + o + 4 * jj);
#pragma unroll
    for (int jj = 0; jj < 4; ++jj) ld[12 + jj] = *(const float4*)(pr3 + o + 4 * jj);
  };

  auto store_stage = [&](int buf) {
    short8 hv0, hv1, tv0, tv1, pv0, pv1;
#pragma unroll
    for (int c = 0; c < 16; ++c) {
      const int v = c >> 2, e = c & 3;
      float x0 = ((const float*)&ld[v])[e];
      float x1 = ((const float*)&ld[4 + v])[e];
      float y0 = ((const float*)&ld[8 + v])[e];
      float y1 = ((const float*)&ld[12 + v])[e];
      float h = 0.5f * (x0 + x1);
      float t = 0.5f * (y0 + y1);
      float p = h * t;                       // product in fp32, rounded once
      if (c < 8) { hv0[c] = (short)f2bf(h); tv0[c] = (short)f2bf(t); pv0[c] = (short)f2bf(p); }
      else       { hv1[c-8] = (short)f2bf(h); tv1[c-8] = (short)f2bf(t); pv1[c-8] = (short)f2bf(p); }
    }
    const int c0 = q * 16;
    *(short8*)&sA[buf][0][pairi][c0]     = hv0;
    *(short8*)&sA[buf][0][pairi][c0 + 8] = hv1;
    *(short8*)&sA[buf][1][pairi][c0]     = tv0;
    *(short8*)&sA[buf][1][pairi][c0 + 8] = tv1;
    *(short8*)&sA[buf][2][pairi][c0]     = pv0;
    *(short8*)&sA[buf][2][pairi][c0 + 8] = pv1;
  };

  load_stage(0);
  store_stage(0);

  for (int s = 0; s < 8; ++s) {
    __syncthreads();                       // buf[s&1] ready for all
    const int buf = s & 1;
    if (s < 7) load_stage(s + 1);          // prefetch next stage into regs

#pragma unroll
    for (int kk = 0; kk < 4; ++kk) {       // 4 MFMA k-steps of 32 per stage
      const int koff = kk * 32 + lg * 8;
      short8 ah[2], at2[2], ap[2];
#pragma unroll
      for (int i = 0; i < 2; ++i) {
        ah[i]  = *(const short8*)&sA[buf][0][i * 16 + lr][koff];
        at2[i] = *(const short8*)&sA[buf][1][i * 16 + lr][koff];
        ap[i]  = *(const short8*)&sA[buf][2][i * 16 + lr][koff];
      }
#pragma unroll
      for (int j = 0; j < 4; ++j) {
        // kc = part*32 + s*4 + kk ; short addr = kc*8192 + (w*4+j)*512 + lane*8
        const unsigned short* wp = wb + (size_t)(s * 4 + kk) * 8192 + (size_t)j * 512;
        short8 b0 = *(const short8*)(wp);               // head  (part 0)
        short8 b1 = *(const short8*)(wp + 32 * 8192);   // tail  (part 1)
        short8 b2 = *(const short8*)(wp + 64 * 8192);   // prod  (part 2)
#pragma unroll
        for (int i = 0; i < 2; ++i) {
          acc[i][j] = mfma_bf16(ah[i],  b0, acc[i][j]);
          acc[i][j] = mfma_bf16(at2[i], b1, acc[i][j]);
          acc[i][j] = mfma_bf16(ap[i],  b2, acc[i][j]);
        }
      }
    }
    if (s < 7) store_stage(buf ^ 1);       // write next buffer (barrier-separated)
  }

  // Epilogue: C/D layout row=(lane>>4)*4+reg, col=lane&15
#pragma unroll
  for (int j = 0; j < 4; ++j) {
    const int col  = w * 64 + j * 16 + lr;
    const float bv = bias[col];
#pragma unroll
    for (int i = 0; i < 2; ++i) {
      const size_t rbase = (size_t)(m0 + i * 16 + lg * 4) * NR + col;
#pragma unroll
      for (int r = 0; r < 4; ++r)
        out[rbase + (size_t)r * NR] = acc[i][j][r] + bv;
    }
  }
}

extern "C" void kernel_launch(void* const* d_in, const int* in_sizes, int n_in,
                              void* d_out, int out_size, void* d_ws, size_t ws_size,
                              hipStream_t stream) {
  const int*   pairs = (const int*)d_in[0];
  const float* hs    = (const float*)d_in[1];
  const float* W     = (const float*)d_in[2];
  const float* bias  = (const float*)d_in[3];
  float* out = (float*)d_out;
  unsigned short* WbF = (unsigned short*)d_ws;   // 1.5 MB frag-major bf16 W

  wconv_kernel<<<(96 * 16 * 64) / 256, 256, 0, stream>>>(W, WbF);
  gemm_kernel<<<(NB * NP) / BM, 256, 0, stream>>>(pairs, hs, WbF, bias, out);
}

// Round 5
// 239.397 us; speedup vs baseline: 1.0436x; 1.0436x over previous
//
#include <hip/hip_runtime.h>

#define NB 32
#define NP 512
#define NS 1024
#define NH 1024
#define NR 256
#define K3 3072

#define BM 64
#define BK 64
#define KP 72   // padded LDS pitch in shorts (144 B)

typedef short short8 __attribute__((ext_vector_type(8)));
typedef short short4v __attribute__((ext_vector_type(4)));
typedef __bf16 bf16x8 __attribute__((ext_vector_type(8)));
typedef float f32x4 __attribute__((ext_vector_type(4)));

__device__ __forceinline__ unsigned short f2bf(float f) {
  unsigned u = __builtin_bit_cast(unsigned, f);
  u += 0x7fffu + ((u >> 16) & 1u);   // round-to-nearest-even
  return (unsigned short)(u >> 16);
}

__device__ __forceinline__ f32x4 mfma_bf16(short8 a, short8 b, f32x4 c) {
  return __builtin_amdgcn_mfma_f32_16x16x32_bf16(
      __builtin_bit_cast(bf16x8, a), __builtin_bit_cast(bf16x8, b), c, 0, 0, 0);
}

// W fp32 [256][3072] -> FRAGMENT-MAJOR bf16 in ws:
//   WbF[kc][n16][lane] (short8), kc = k3/32 (96), n16 = n/16 (16), lane = lr+16*lg.
//   A wave's B-fragment load is one contiguous 1 KB burst (16 lines).
__global__ void wconv_kernel(const float* __restrict__ W,
                             unsigned short* __restrict__ WbF) {
  int i = blockIdx.x * blockDim.x + threadIdx.x;   // short8 id, 98304 total
  int lane = i & 63, n16 = (i >> 6) & 15, kc = i >> 10;
  int lr = lane & 15, lg = lane >> 4;
  const float* src = W + (size_t)(n16 * 16 + lr) * K3 + kc * 32 + lg * 8;
  float4 a = *(const float4*)src;
  float4 b = *(const float4*)(src + 4);
  short8 o;
  o[0] = (short)f2bf(a.x); o[1] = (short)f2bf(a.y);
  o[2] = (short)f2bf(a.z); o[3] = (short)f2bf(a.w);
  o[4] = (short)f2bf(b.x); o[5] = (short)f2bf(b.y);
  o[6] = (short)f2bf(b.z); o[7] = (short)f2bf(b.w);
  *(short8*)(WbF + (size_t)i * 8) = o;
}

// Fused gather + 3-part bf16 MFMA GEMM.
// Grid: 256 blocks (M-tiles of 64 pairs), 512 threads = 8 waves; wave w owns
// cols [w*32, w*32+32), tile 64x32. Gather is LANE-PACKED: on each load
// instruction consecutive lanes read consecutive 16-B chunks (128 B contiguous
// per pair-row -> 16 lines/instr, the packing floor), cutting TCP line lookups
// 2x vs R3 / 4x vs R4. Blocks are XCD-swizzled so one batch's 8 blocks share
// an XCD (L2 slab locality + ~2x within-batch row reuse).
__global__ __launch_bounds__(512, 2) void gemm_kernel(
    const int* __restrict__ pairs, const float* __restrict__ hs,
    const unsigned short* __restrict__ WbF, const float* __restrict__ bias,
    float* __restrict__ out) {
  __shared__ __align__(16) unsigned short sA[2][3][BM][KP];  // 55296 B

  const int tid = threadIdx.x;
  const int blk = blockIdx.x;
  // XCD swizzle: consecutive blockIdx round-robin over 8 XCDs; give XCD x the
  // batches 4x..4x+3 so a batch's 8 M-tiles stay in one XCD's L2.
  const int x     = blk & 7;
  const int jb    = blk >> 3;
  const int batch = x * 4 + (jb >> 3);
  const int mtile = jb & 7;
  const int m0    = (batch * 8 + mtile) * BM;

  // --- gather assignment: 8 threads per pair, thread q covers float-cols
  //     {4q..4q+4} and {4q+32..4q+36} of each of the 4 source rows ---
  const int pairi = tid >> 3;
  const int q     = tid & 7;
  int4 pr = ((const int4*)pairs)[m0 + pairi];
  const float* hb = hs + (size_t)batch * NS * NH;
  const float* rp[4];
  rp[0] = hb + (size_t)pr.x * NH + 4 * q;   // h_start
  rp[1] = hb + (size_t)pr.y * NH + 4 * q;   // h_end
  rp[2] = hb + (size_t)pr.z * NH + 4 * q;   // t_start
  rp[3] = hb + (size_t)pr.w * NH + 4 * q;   // t_end

  // --- MFMA lane mapping ---
  const int lane = tid & 63;
  const int w    = tid >> 6;           // wave 0..7, cols w*32..w*32+32
  const int lr   = lane & 15;
  const int lg   = lane >> 4;

  // frag-major W: short addr = kc*8192 + n16*512 + lane*8; this wave: n16 = w*2+j
  const unsigned short* wb = WbF + (size_t)(w * 2) * 512 + (size_t)lane * 8;

  f32x4 acc[4][2];
#pragma unroll
  for (int i = 0; i < 4; ++i)
#pragma unroll
    for (int j = 0; j < 2; ++j) acc[i][j] = (f32x4){0.f, 0.f, 0.f, 0.f};

  // gather prefetch regs: ld[jj]: row = jj>>1, col-half = jj&1
  float4 ld[8];

  auto load_stage = [&](int s) {
    const int o = s * BK;
#pragma unroll
    for (int jj = 0; jj < 8; ++jj)
      ld[jj] = *(const float4*)(rp[jj >> 1] + o + 32 * (jj & 1));
  };

  auto store_stage = [&](int buf) {
#pragma unroll
    for (int c = 0; c < 2; ++c) {        // col-half
      short4v hv, tv, pv;
#pragma unroll
      for (int e = 0; e < 4; ++e) {
        float h = 0.5f * (((const float*)&ld[0 + c])[e] + ((const float*)&ld[2 + c])[e]);
        float t = 0.5f * (((const float*)&ld[4 + c])[e] + ((const float*)&ld[6 + c])[e]);
        float p = h * t;                 // product in fp32, rounded once
        hv[e] = (short)f2bf(h); tv[e] = (short)f2bf(t); pv[e] = (short)f2bf(p);
      }
      const int c0 = 4 * q + 32 * c;
      *(short4v*)&sA[buf][0][pairi][c0] = hv;
      *(short4v*)&sA[buf][1][pairi][c0] = tv;
      *(short4v*)&sA[buf][2][pairi][c0] = pv;
    }
  };

  load_stage(0);
  store_stage(0);

  for (int s = 0; s < 16; ++s) {
    __syncthreads();                       // buf[s&1] ready for all
    const int buf = s & 1;
    if (s < 15) load_stage(s + 1);         // prefetch next stage into regs

#pragma unroll
    for (int ks = 0; ks < 2; ++ks) {       // 2 MFMA k-steps of 32 per stage
      const int koff = ks * 32 + lg * 8;
      short8 ah[4], at4[4], ap[4];
#pragma unroll
      for (int i = 0; i < 4; ++i) {
        ah[i]  = *(const short8*)&sA[buf][0][i * 16 + lr][koff];
        at4[i] = *(const short8*)&sA[buf][1][i * 16 + lr][koff];
        ap[i]  = *(const short8*)&sA[buf][2][i * 16 + lr][koff];
      }
#pragma unroll
      for (int j = 0; j < 2; ++j) {
        // kc = part*32 + s*2 + ks ; short addr = kc*8192 + (w*2+j)*512 + lane*8
        const unsigned short* wp = wb + (size_t)(s * 2 + ks) * 8192 + (size_t)j * 512;
        short8 b0 = *(const short8*)(wp);               // head  (part 0)
        short8 b1 = *(const short8*)(wp + 32 * 8192);   // tail  (part 1)
        short8 b2 = *(const short8*)(wp + 64 * 8192);   // prod  (part 2)
#pragma unroll
        for (int i = 0; i < 4; ++i) {
          acc[i][j] = mfma_bf16(ah[i],  b0, acc[i][j]);
          acc[i][j] = mfma_bf16(at4[i], b1, acc[i][j]);
          acc[i][j] = mfma_bf16(ap[i],  b2, acc[i][j]);
        }
      }
    }
    if (s < 15) store_stage(buf ^ 1);      // write next buffer (barrier-separated)
  }

  // Epilogue: C/D layout row=(lane>>4)*4+reg, col=lane&15
#pragma unroll
  for (int j = 0; j < 2; ++j) {
    const int col  = w * 32 + j * 16 + lr;
    const float bv = bias[col];
#pragma unroll
    for (int i = 0; i < 4; ++i) {
      const size_t rbase = (size_t)(m0 + i * 16 + lg * 4) * NR + col;
#pragma unroll
      for (int r = 0; r < 4; ++r)
        out[rbase + (size_t)r * NR] = acc[i][j][r] + bv;
    }
  }
}

extern "C" void kernel_launch(void* const* d_in, const int* in_sizes, int n_in,
                              void* d_out, int out_size, void* d_ws, size_t ws_size,
                              hipStream_t stream) {
  const int*   pairs = (const int*)d_in[0];
  const float* hs    = (const float*)d_in[1];
  const float* W     = (const float*)d_in[2];
  const float* bias  = (const float*)d_in[3];
  float* out = (float*)d_out;
  unsigned short* WbF = (unsigned short*)d_ws;   // 1.5 MB frag-major bf16 W

  wconv_kernel<<<(96 * 16 * 64) / 256, 256, 0, stream>>>(W, WbF);
  gemm_kernel<<<(NB * NP) / BM, 512, 0, stream>>>(pairs, hs, WbF, bias, out);
}

// Round 6
// 231.965 us; speedup vs baseline: 1.0770x; 1.0320x over previous
//
#include <hip/hip_runtime.h>

#define NB 32
#define NP 512
#define NS 1024
#define NH 1024
#define NR 256
#define K3 3072

#define BM 64
#define BK 64

typedef short short8 __attribute__((ext_vector_type(8)));
typedef short short4v __attribute__((ext_vector_type(4)));
typedef __bf16 bf16x8 __attribute__((ext_vector_type(8)));
typedef float f32x4 __attribute__((ext_vector_type(4)));

__device__ __forceinline__ unsigned short f2bf(float f) {
  unsigned u = __builtin_bit_cast(unsigned, f);
  u += 0x7fffu + ((u >> 16) & 1u);   // round-to-nearest-even
  return (unsigned short)(u >> 16);
}

__device__ __forceinline__ f32x4 mfma_bf16(short8 a, short8 b, f32x4 c) {
  return __builtin_amdgcn_mfma_f32_16x16x32_bf16(
      __builtin_bit_cast(bf16x8, a), __builtin_bit_cast(bf16x8, b), c, 0, 0, 0);
}

// W fp32 [256][3072] -> FRAGMENT-MAJOR bf16 in ws:
//   WbF[kc][n16][lane] (short8), kc = k3/32 (96), n16 = n/16 (16), lane = lr+16*lg.
//   A wave's B-fragment load is one contiguous 1 KB burst (16 lines).
__global__ void wconv_kernel(const float* __restrict__ W,
                             unsigned short* __restrict__ WbF) {
  int i = blockIdx.x * blockDim.x + threadIdx.x;   // short8 id, 98304 total
  int lane = i & 63, n16 = (i >> 6) & 15, kc = i >> 10;
  int lr = lane & 15, lg = lane >> 4;
  const float* src = W + (size_t)(n16 * 16 + lr) * K3 + kc * 32 + lg * 8;
  float4 a = *(const float4*)src;
  float4 b = *(const float4*)(src + 4);
  short8 o;
  o[0] = (short)f2bf(a.x); o[1] = (short)f2bf(a.y);
  o[2] = (short)f2bf(a.z); o[3] = (short)f2bf(a.w);
  o[4] = (short)f2bf(b.x); o[5] = (short)f2bf(b.y);
  o[6] = (short)f2bf(b.z); o[7] = (short)f2bf(b.w);
  *(short8*)(WbF + (size_t)i * 8) = o;
}

// Fused gather + 3-part bf16 MFMA GEMM.
// Structure: W fragments register-prefetched ONE STAGE AHEAD (ping-pong
// wcur/wnxt) and issued BEFORE the gather loads, so no MFMA ever waits on the
// ordered vmcnt queue behind a random-latency gather. LDS A-tiles are
// XOR-swizzled (chunk ^ row&7, pitch 64) for exact uniform bank spread.
__global__ __launch_bounds__(512, 2) void gemm_kernel(
    const int* __restrict__ pairs, const float* __restrict__ hs,
    const unsigned short* __restrict__ WbF, const float* __restrict__ bias,
    float* __restrict__ out) {
  __shared__ __align__(16) unsigned short sA[2][3][BM][64];  // 49152 B

  const int tid = threadIdx.x;
  const int blk = blockIdx.x;
  // XCD swizzle: blockIdx round-robins over 8 XCDs; give XCD x batches
  // 4x..4x+3 so a batch's 8 M-tiles share one XCD's L2 (R5: FETCH 122->63 MB).
  const int x     = blk & 7;
  const int jb    = blk >> 3;
  const int batch = x * 4 + (jb >> 3);
  const int mtile = jb & 7;
  const int m0    = (batch * 8 + mtile) * BM;

  // gather: 8 threads per pair; thread q covers float-cols {4q..4q+3} and
  // {4q+32..4q+35} of each of the 4 source rows (lane-packed, 16 lines/instr)
  const int pairi = tid >> 3;
  const int q     = tid & 7;
  int4 pr = ((const int4*)pairs)[m0 + pairi];
  const float* hb = hs + (size_t)batch * NS * NH;
  const float* rp[4];
  rp[0] = hb + (size_t)pr.x * NH + 4 * q;   // h_start
  rp[1] = hb + (size_t)pr.y * NH + 4 * q;   // h_end
  rp[2] = hb + (size_t)pr.z * NH + 4 * q;   // t_start
  rp[3] = hb + (size_t)pr.w * NH + 4 * q;   // t_end

  // MFMA lane mapping
  const int lane = tid & 63;
  const int w    = tid >> 6;           // wave 0..7, cols w*32..w*32+32
  const int lr   = lane & 15;
  const int lg   = lane >> 4;

  // frag-major W: short addr = kc*8192 + n16*512 + lane*8; this wave: n16=2w+j
  const unsigned short* wbase = WbF + (size_t)(w * 2) * 512 + (size_t)lane * 8;

  f32x4 acc[4][2];
#pragma unroll
  for (int i = 0; i < 4; ++i)
#pragma unroll
    for (int j = 0; j < 2; ++j) acc[i][j] = (f32x4){0.f, 0.f, 0.f, 0.f};

  float4 ld[8];                 // gather prefetch: ld[jj]: row=jj>>1, half=jj&1
  short8 wcur[12], wnxt[12];    // W frags: idx = part*4 + ks*2 + j

  auto load_w = [&](int s, short8* wd) {
#pragma unroll
    for (int part = 0; part < 3; ++part)
#pragma unroll
      for (int ks = 0; ks < 2; ++ks)
#pragma unroll
        for (int j = 0; j < 2; ++j)
          wd[part * 4 + ks * 2 + j] = *(const short8*)(
              wbase + (size_t)(part * 32 + s * 2 + ks) * 8192 + (size_t)j * 512);
  };

  auto load_gather = [&](int s) {
    const int o = s * BK;
#pragma unroll
    for (int jj = 0; jj < 8; ++jj)
      ld[jj] = *(const float4*)(rp[jj >> 1] + o + 32 * (jj & 1));
  };

  auto store_stage = [&](int buf) {
#pragma unroll
    for (int c = 0; c < 2; ++c) {        // col-half
      short4v hv, tv, pv;
#pragma unroll
      for (int e = 0; e < 4; ++e) {
        float h = 0.5f * (((const float*)&ld[0 + c])[e] + ((const float*)&ld[2 + c])[e]);
        float t = 0.5f * (((const float*)&ld[4 + c])[e] + ((const float*)&ld[6 + c])[e]);
        float p = h * t;                 // product in fp32, rounded once
        hv[e] = (short)f2bf(h); tv[e] = (short)f2bf(t); pv[e] = (short)f2bf(p);
      }
      const int chunkI = (q >> 1) + 4 * c;
      const int col = ((chunkI ^ (pairi & 7)) * 8) + (q & 1) * 4;  // XOR swizzle
      *(short4v*)&sA[buf][0][pairi][col] = hv;
      *(short4v*)&sA[buf][1][pairi][col] = tv;
      *(short4v*)&sA[buf][2][pairi][col] = pv;
    }
  };

  auto compute = [&](int buf, short8* wc) {
#pragma unroll
    for (int ks = 0; ks < 2; ++ks) {
      short8 ah[4], at4[4], ap[4];
      const int col = (((ks * 4 + lg) ^ (lr & 7)) * 8);            // XOR swizzle
#pragma unroll
      for (int i = 0; i < 4; ++i) {
        ah[i]  = *(const short8*)&sA[buf][0][i * 16 + lr][col];
        at4[i] = *(const short8*)&sA[buf][1][i * 16 + lr][col];
        ap[i]  = *(const short8*)&sA[buf][2][i * 16 + lr][col];
      }
#pragma unroll
      for (int j = 0; j < 2; ++j)
#pragma unroll
        for (int i = 0; i < 4; ++i) {
          acc[i][j] = mfma_bf16(ah[i],  wc[0 + ks * 2 + j], acc[i][j]);
          acc[i][j] = mfma_bf16(at4[i], wc[4 + ks * 2 + j], acc[i][j]);
          acc[i][j] = mfma_bf16(ap[i],  wc[8 + ks * 2 + j], acc[i][j]);
        }
    }
  };

  // prologue: W(0) -> wcur, gather(0) -> LDS buf 0
  load_w(0, wcur);
  load_gather(0);
  store_stage(0);

  auto stage = [&](int s, short8* wc, short8* wn) {
    __syncthreads();                     // buf[s&1] + wc ready
    const int buf = s & 1;
    if (s < 15) {
      load_w(s + 1, wn);                 // W FIRST in the vmem queue
      load_gather(s + 1);                // slow gathers AFTER
    }
    compute(buf, wc);                    // consumes registers only (+ LDS)
    if (s < 15) store_stage(buf ^ 1);    // tail: waits gathers (full-stage slack)
  };

#pragma unroll 1
  for (int sp = 0; sp < 8; ++sp) {       // ping-pong W register buffers
    stage(2 * sp,     wcur, wnxt);
    stage(2 * sp + 1, wnxt, wcur);
  }

  // Epilogue: C/D layout row=(lane>>4)*4+reg, col=lane&15
#pragma unroll
  for (int j = 0; j < 2; ++j) {
    const int col  = w * 32 + j * 16 + lr;
    const float bv = bias[col];
#pragma unroll
    for (int i = 0; i < 4; ++i) {
      const size_t rbase = (size_t)(m0 + i * 16 + lg * 4) * NR + col;
#pragma unroll
      for (int r = 0; r < 4; ++r)
        out[rbase + (size_t)r * NR] = acc[i][j][r] + bv;
    }
  }
}

extern "C" void kernel_launch(void* const* d_in, const int* in_sizes, int n_in,
                              void* d_out, int out_size, void* d_ws, size_t ws_size,
                              hipStream_t stream) {
  const int*   pairs = (const int*)d_in[0];
  const float* hs    = (const float*)d_in[1];
  const float* W     = (const float*)d_in[2];
  const float* bias  = (const float*)d_in[3];
  float* out = (float*)d_out;
  unsigned short* WbF = (unsigned short*)d_ws;   // 1.5 MB frag-major bf16 W

  wconv_kernel<<<(96 * 16 * 64) / 256, 256, 0, stream>>>(W, WbF);
  gemm_kernel<<<(NB * NP) / BM, 512, 0, stream>>>(pairs, hs, WbF, bias, out);
}